// Round 4
// baseline (144.890 us; speedup 1.0000x reference)
//
#include <hip/hip_runtime.h>
#include <stdint.h>

// N=4 batches, C=256, S=16, H*W=1024, K1=S*C=4096, 3 layers.
#define CC   256
#define SSL  16
#define NB   4
#define HWP  1024
#define K1   4096
#define EPSV 1e-5f

typedef __attribute__((ext_vector_type(8))) short bf16x8;
typedef __attribute__((ext_vector_type(4))) float f32x4;

__device__ __forceinline__ ushort f2bf(float f) {
    uint32_t u = __float_as_uint(f);
    uint32_t r = (u + 0x7FFFu + ((u >> 16) & 1u)) >> 16;   // RNE
    return (ushort)r;
}

// ---------------------------------------------------------------------------
// prep: ONE depth-1 kernel, jobs split by blockIdx range (all read only inputs):
//   [0,256)     feats [n][c][p] fp32 -> fT [n][p][c] bf16 (LDS transpose)
//   [256,1024)  conv_w fp32 -> bf16 copy
//   [1024,1088) msst with SELF-COMPUTED flags: block (n, a-tile, b-tile) loads the
//               full adj column block [256a][64b] (needed for flags anyway),
//               computes all/any flags locally, gates+writes its 64-a slice:
//               msst[n][b][k*256+a] = bf16(sel(flag[k,b], m[a,b]))  (B^T, K-contig)
__global__ __launch_bounds__(256) void prep_kernel(const float* __restrict__ adj,
                                                   const float* __restrict__ feats,
                                                   const float* __restrict__ conv_w,
                                                   ushort* __restrict__ fT,
                                                   ushort* __restrict__ wb,
                                                   ushort* __restrict__ msst) {
    __shared__ char smem[67584];          // max over branches
    const int bid = blockIdx.x;
    const int t = threadIdx.x;
    if (bid < 256) {                      // ---- featsT ----
        float (*Ts)[68] = (float(*)[68])smem;
        const int n = bid >> 6, r = bid & 63;
        const int c0 = (r >> 4) * 64, p0 = (r & 15) * 64;
        const float* src = feats + ((size_t)n * CC + c0) * HWP + p0;
        const int cr = t >> 2, pq = (t & 3) * 16;
#pragma unroll
        for (int i = 0; i < 4; ++i)
            *(float4*)&Ts[cr][pq + i * 4] = *(const float4*)(src + (size_t)cr * HWP + pq + i * 4);
        __syncthreads();
        const int pl = t >> 2, cc0 = (t & 3) * 16;
        ushort* dst = fT + ((size_t)n * HWP + p0 + pl) * CC + c0 + cc0;
#pragma unroll
        for (int a4 = 0; a4 < 4; ++a4) {
            ushort4 o;
            o.x = f2bf(Ts[cc0 + a4 * 4 + 0][pl]);
            o.y = f2bf(Ts[cc0 + a4 * 4 + 1][pl]);
            o.z = f2bf(Ts[cc0 + a4 * 4 + 2][pl]);
            o.w = f2bf(Ts[cc0 + a4 * 4 + 3][pl]);
            *(ushort4*)(dst + a4 * 4) = o;
        }
    } else if (bid < 1024) {              // ---- convw bf16 ----
        const int c = bid - 256;
        const int idx = (c * 256 + t) * 16;
#pragma unroll
        for (int i = 0; i < 4; ++i) {
            float4 v = *(const float4*)(conv_w + idx + i * 4);
            ushort4 o = {f2bf(v.x), f2bf(v.y), f2bf(v.z), f2bf(v.w)};
            *(ushort4*)(wb + idx + i * 4) = o;
        }
    } else {                              // ---- msst (self-flags) ----
        float (*Mc)[65] = (float(*)[65])smem;            // [256][65] fp32
        uint8_t* fl = (uint8_t*)(smem + 66560);          // [16][64]
        const int q = bid - 1024;
        const int n = q >> 4, at = (q >> 2) & 3, bt = q & 3;
        const float* m = adj + (size_t)n * CC * CC + bt * 64;
        // load full column block [256a][64b], coalesced 64B segments
#pragma unroll
        for (int it = 0; it < 16; ++it) {
            const int r = it * 16 + (t >> 4), c = (t & 15) * 4;
            *(float4*)&Mc[r][c] = *(const float4*)(m + (size_t)r * CC + c);
        }
        __syncthreads();
        // flags: 16k x 64b pairs, 4 per thread
#pragma unroll
        for (int e = 0; e < 4; ++e) {
            const int pair = t + e * 256;
            const int k = pair >> 6, b = pair & 63;
            bool allp = true, anyp = false;
#pragma unroll
            for (int i = 0; i < 16; ++i) {
                const bool p = Mc[k * 16 + i][b] > 0.0f;
                allp = allp && p;
                anyp = anyp || p;
            }
            fl[k * 64 + b] = allp ? (uint8_t)2 : (anyp ? (uint8_t)1 : (uint8_t)0);
        }
        __syncthreads();
        // gate & write this block's a-slice (64 a), all 16 k
        const int b = t >> 2, a0 = at * 64 + (t & 3) * 16;
        ushort bx[16], bp[16];
#pragma unroll
        for (int e = 0; e < 16; ++e) {
            const float x = Mc[a0 + e][b];
            bx[e] = f2bf(x);
            bp[e] = f2bf(fmaxf(x, 0.0f));
        }
        ushort* dst = msst + ((size_t)(n * CC + bt * 64 + b)) * K1 + a0;
#pragma unroll
        for (int k = 0; k < 16; ++k) {
            const uint8_t f = fl[k * 64 + b];
            ushort* dk = dst + k * CC;
#pragma unroll
            for (int a4 = 0; a4 < 4; ++a4) {
                ushort4 o;
                o.x = (f == 2) ? bx[a4 * 4 + 0] : ((f == 1) ? bp[a4 * 4 + 0] : (ushort)0);
                o.y = (f == 2) ? bx[a4 * 4 + 1] : ((f == 1) ? bp[a4 * 4 + 1] : (ushort)0);
                o.z = (f == 2) ? bx[a4 * 4 + 2] : ((f == 1) ? bp[a4 * 4 + 2] : (ushort)0);
                o.w = (f == 2) ? bx[a4 * 4 + 3] : ((f == 1) ? bp[a4 * 4 + 3] : (ushort)0);
                *(ushort4*)(dk + a4 * 4) = o;
            }
        }
    }
}

// ---------------------------------------------------------------------------
// W_eff GEMM, NO split-K. 64x64 tile, K=4096, BK=64, register-prefetch dbuf.
// BN row-scale folded; writes bf16 Ws[ln][o][b] directly (no reduce kernel).
// Grid 256 blocks; decode x = m*16 + g with g<12 (64 idle): XCD = x%8 = g%8, so
// the 16 blocks sharing an A-panel (l,ot) co-locate on one XCD's L2.
__global__ __launch_bounds__(256) void weff_mfma(const ushort* __restrict__ Aw,
                                                 const ushort* __restrict__ Bm,
                                                 const float* __restrict__ gamma,
                                                 const float* __restrict__ var,
                                                 ushort* __restrict__ Ws) {
    const int x = blockIdx.x;
    const int g = x & 15;
    if (g >= 12) return;                  // 64 idle blocks exit immediately
    const int mI = x >> 4;
    const int l = g >> 2, ot = g & 3;
    const int n = mI >> 2, bt = mI & 3;
    const int ln = l * 4 + n;
    const int o0 = ot * 64, b0 = bt * 64;
    const ushort* A = Aw + (size_t)l * CC * K1;
    const ushort* B = Bm + (size_t)n * CC * K1;
    __shared__ ushort Al[64][72];         // [row][k], BK=64 + 8 pad
    __shared__ ushort Bl[64][72];
    const int t = threadIdx.x;
    const int wv = t >> 6, L = t & 63;
    const int wr = (wv >> 1) * 32, wc = (wv & 1) * 32;
    const int l16 = L & 15, q = L >> 4;
    const int r0 = t >> 2, kq0 = (t & 3) * 16;
    f32x4 acc[2][2];
#pragma unroll
    for (int i = 0; i < 2; ++i)
#pragma unroll
        for (int j = 0; j < 2; ++j)
            acc[i][j] = (f32x4){0.f, 0.f, 0.f, 0.f};

    const ushort* Ap = A + (size_t)(o0 + r0) * K1 + kq0;
    const ushort* Bp = B + (size_t)(b0 + r0) * K1 + kq0;
    int4 a0v = *(const int4*)(Ap);
    int4 a1v = *(const int4*)(Ap + 8);
    int4 b0v = *(const int4*)(Bp);
    int4 b1v = *(const int4*)(Bp + 8);

    for (int kt = 0; kt < 64; ++kt) {
        __syncthreads();                  // previous iter's ds_reads done
        *(int4*)&Al[r0][kq0] = a0v;
        *(int4*)&Al[r0][kq0 + 8] = a1v;
        *(int4*)&Bl[r0][kq0] = b0v;
        *(int4*)&Bl[r0][kq0 + 8] = b1v;
        __syncthreads();
        if (kt < 63) {                    // prefetch next tile into regs
            const int kk = (kt + 1) * 64;
            a0v = *(const int4*)(Ap + kk);
            a1v = *(const int4*)(Ap + kk + 8);
            b0v = *(const int4*)(Bp + kk);
            b1v = *(const int4*)(Bp + kk + 8);
        }
#pragma unroll
        for (int ks = 0; ks < 2; ++ks) {
            bf16x8 af[2], bfr[2];
#pragma unroll
            for (int i = 0; i < 2; ++i)
                af[i] = *(const bf16x8*)&Al[wr + i * 16 + l16][ks * 32 + q * 8];
#pragma unroll
            for (int j = 0; j < 2; ++j)
                bfr[j] = *(const bf16x8*)&Bl[wc + j * 16 + l16][ks * 32 + q * 8];
#pragma unroll
            for (int i = 0; i < 2; ++i)
#pragma unroll
                for (int j = 0; j < 2; ++j)
                    acc[i][j] = __builtin_amdgcn_mfma_f32_16x16x32_bf16(af[i], bfr[j], acc[i][j], 0, 0, 0);
        }
    }

    // BN fold + bf16 store: D col=lane&15 (b), row=quad*4+reg (o)
#pragma unroll
    for (int i = 0; i < 2; ++i)
#pragma unroll
        for (int j = 0; j < 2; ++j) {
            const int ob = o0 + wr + i * 16 + q * 4;
            const int b = b0 + wc + j * 16 + l16;
#pragma unroll
            for (int r = 0; r < 4; ++r) {
                const int o = ob + r;
                const float sc = gamma[l * CC + o] * rsqrtf(var[l * CC + o] + EPSV);
                Ws[((size_t)ln * CC + o) * CC + b] = f2bf(acc[i][j][r] * sc);
            }
        }
}

// ---------------------------------------------------------------------------
// Layer GEMM (bf16 MFMA, TN): yT[p][o] = sum_b xT[p][b] * Ws[o][b]; epilogue
// relu(acc+bias2[o]); writes fp32 out[n][o][p] + bf16 xT[p][o] (skipped if null).
// Round-2 structure (measured fastest). 64x64 tile, 4 waves x (2x2). Grid (64,4).
__global__ __launch_bounds__(256) void layer_mfma(const ushort* __restrict__ xT,
                                                  const ushort* __restrict__ Wsl,
                                                  const float* __restrict__ convb_l,
                                                  const float* __restrict__ gamma_l,
                                                  const float* __restrict__ beta_l,
                                                  const float* __restrict__ mean_l,
                                                  const float* __restrict__ var_l,
                                                  float* __restrict__ outl,
                                                  ushort* __restrict__ xTn) {
    const int n = blockIdx.y;
    const int pt = blockIdx.x & 15, ot = blockIdx.x >> 4;
    const ushort* Axt = xT + (size_t)n * HWP * CC + (size_t)pt * 64 * CC;
    const ushort* Bw  = Wsl + (size_t)n * CC * CC + (size_t)ot * 64 * CC;
    __shared__ ushort Al[64][40];
    __shared__ ushort Bl[64][40];
    const int t = threadIdx.x;
    const int wv = t >> 6, L = t & 63;
    const int wr = (wv >> 1) * 32, wc = (wv & 1) * 32;
    const int l16 = L & 15, q = L >> 4;
    const int r0 = t >> 2, kq0 = (t & 3) * 8;
    f32x4 acc[2][2];
#pragma unroll
    for (int i = 0; i < 2; ++i)
#pragma unroll
        for (int j = 0; j < 2; ++j)
            acc[i][j] = (f32x4){0.f, 0.f, 0.f, 0.f};

    int4 av = *(const int4*)(Axt + (size_t)r0 * CC + kq0);
    int4 bv = *(const int4*)(Bw + (size_t)r0 * CC + kq0);
    for (int kt = 0; kt < 8; ++kt) {
        __syncthreads();
        *(int4*)&Al[r0][kq0] = av;
        *(int4*)&Bl[r0][kq0] = bv;
        __syncthreads();
        if (kt < 7) {
            const int kk = (kt + 1) * 32;
            av = *(const int4*)(Axt + (size_t)r0 * CC + kk + kq0);
            bv = *(const int4*)(Bw + (size_t)r0 * CC + kk + kq0);
        }
        bf16x8 af[2], bfr[2];
#pragma unroll
        for (int i = 0; i < 2; ++i)
            af[i] = *(const bf16x8*)&Al[wr + i * 16 + l16][q * 8];
#pragma unroll
        for (int j = 0; j < 2; ++j)
            bfr[j] = *(const bf16x8*)&Bl[wc + j * 16 + l16][q * 8];
#pragma unroll
        for (int i = 0; i < 2; ++i)
#pragma unroll
            for (int j = 0; j < 2; ++j)
                acc[i][j] = __builtin_amdgcn_mfma_f32_16x16x32_bf16(af[i], bfr[j], acc[i][j], 0, 0, 0);
    }

    float* outn = outl + (size_t)n * CC * HWP;
    ushort* xtn = xTn ? xTn + (size_t)n * HWP * CC : (ushort*)0;
#pragma unroll
    for (int i = 0; i < 2; ++i)
#pragma unroll
        for (int j = 0; j < 2; ++j) {
            const int p = pt * 64 + wr + i * 16 + q * 4;   // D row
            const int o = ot * 64 + wc + j * 16 + l16;     // D col
            const float sc = gamma_l[o] * rsqrtf(var_l[o] + EPSV);
            const float b2 = sc * (convb_l[o] - mean_l[o]) + beta_l[o];
            float v0 = fmaxf(acc[i][j][0] + b2, 0.f);
            float v1 = fmaxf(acc[i][j][1] + b2, 0.f);
            float v2 = fmaxf(acc[i][j][2] + b2, 0.f);
            float v3 = fmaxf(acc[i][j][3] + b2, 0.f);
            *(float4*)(outn + (size_t)o * HWP + p) = (float4){v0, v1, v2, v3};
            if (xtn) {
                xtn[(size_t)(p + 0) * CC + o] = f2bf(v0);
                xtn[(size_t)(p + 1) * CC + o] = f2bf(v1);
                xtn[(size_t)(p + 2) * CC + o] = f2bf(v2);
                xtn[(size_t)(p + 3) * CC + o] = f2bf(v3);
            }
        }
}

// ---------------------------------------------------------------------------
extern "C" void kernel_launch(void* const* d_in, const int* in_sizes, int n_in,
                              void* d_out, int out_size, void* d_ws, size_t ws_size,
                              hipStream_t stream) {
    const float* feats  = (const float*)d_in[0];
    const float* adj    = (const float*)d_in[1];
    const float* conv_w = (const float*)d_in[2];
    const float* conv_b = (const float*)d_in[3];
    const float* gamma  = (const float*)d_in[4];
    const float* beta   = (const float*)d_in[5];
    const float* mean   = (const float*)d_in[6];
    const float* var    = (const float*)d_in[7];
    float* out = (float*)d_out;

    // ws layout (bytes): convwb 6MB | msst 8MB | Ws 1.5MB | fT0 2MB | xT1 2MB | xT2 2MB
    char* ws = (char*)d_ws;
    ushort* convwb = (ushort*)ws;
    ushort* msst   = (ushort*)(ws + 6291456);
    ushort* Wsb    = (ushort*)(ws + 6291456 + 8388608);
    ushort* fT0    = (ushort*)(ws + 6291456 + 8388608 + 1572864);
    ushort* xT1    = (ushort*)(ws + 6291456 + 8388608 + 1572864 + 2097152);
    ushort* xT2    = (ushort*)(ws + 6291456 + 8388608 + 1572864 + 2097152 + 2097152);

    prep_kernel<<<1088, 256, 0, stream>>>(adj, feats, conv_w, fT0, convwb, msst);
    weff_mfma<<<256, 256, 0, stream>>>(convwb, msst, gamma, var, Wsb);

    const ushort* xin[3] = {fT0, xT1, xT2};
    ushort* xout[3] = {xT1, xT2, (ushort*)0};
    for (int l = 0; l < 3; ++l) {
        layer_mfma<<<dim3(64, NB), 256, 0, stream>>>(
            xin[l], Wsb + (size_t)l * NB * CC * CC,
            conv_b + l * CC, gamma + l * CC, beta + l * CC, mean + l * CC, var + l * CC,
            out + (size_t)l * NB * CC * HWP, xout[l]);
    }
}